// Round 2
// baseline (411.983 us; speedup 1.0000x reference)
//
#include <hip/hip_runtime.h>

// ---------------------------------------------------------------------------
// ReliabilityGatedCrossAttention — MFMA bf16 (hi/lo split for fp32-level
// accuracy) implementation for gfx950.
//
// Pipeline:
//   1. wsplit_kernel    : split+transpose Wq/Wk/Wv/Wo -> bf16 hi/lo, [n][k]
//   2. proj3_kernel     : Q = q@Wq+bq ; K = (kv@Wk+bk)*r ; V = (kv@Wv+bv)*r
//                         (3-MFMA split GEMM, writes Q/K hi+lo bf16, V bf16)
//   3. transpose_v      : V[b][k][d] -> Vt[b][d][k]   (for PV B-fragments)
//   4. attn_kernel      : two-pass, no-max softmax: pass1 rowsum of
//                         exp(S/8)*r ; pass2 p = exp(S/8)*r/s, writes
//                         attn_mean (head-avg) + PV -> AO hi/lo bf16
//   5. final_kernel     : out = AO@Wo + bo  (fp32 output)
// ---------------------------------------------------------------------------

typedef __attribute__((ext_vector_type(8))) short short8;
typedef __attribute__((ext_vector_type(4))) float f32x4;

#define MFMA16(A, B, C) __builtin_amdgcn_mfma_f32_16x16x32_bf16((A), (B), (C), 0, 0, 0)

__device__ __forceinline__ unsigned short f2bf(float f) {
    union { float f; unsigned int u; } v; v.f = f;
    unsigned int u = v.u;
    return (unsigned short)((u + 0x7fffu + ((u >> 16) & 1u)) >> 16);
}
__device__ __forceinline__ float bf2f(unsigned short h) {
    union { unsigned int u; float f; } v; v.u = ((unsigned int)h) << 16;
    return v.f;
}
__device__ __forceinline__ short8 ld8(const unsigned short* p) {
    return *reinterpret_cast<const short8*>(p);
}

// ---------------------------------------------------------------------------
// 1. Split + transpose the four 256x256 weight matrices into bf16 hi/lo,
//    stored transposed [n][k] so B-fragments read 8 consecutive k (16B).
// ---------------------------------------------------------------------------
__global__ void wsplit_kernel(const float* __restrict__ Wq, const float* __restrict__ Wk,
                              const float* __restrict__ Wv, const float* __restrict__ Wo,
                              unsigned short* __restrict__ WThi, unsigned short* __restrict__ WTlo) {
    int e = blockIdx.x * 256 + threadIdx.x;   // 0 .. 262143
    int m = e >> 16;
    int idx = e & 65535;
    int k = idx >> 8, n = idx & 255;
    const float* W = (m == 0) ? Wq : (m == 1) ? Wk : (m == 2) ? Wv : Wo;
    float v = W[idx];                          // W[k][n]
    unsigned short h = f2bf(v);
    WThi[m * 65536 + n * 256 + k] = h;
    WTlo[m * 65536 + n * 256 + k] = f2bf(v - bf2f(h));
}

// ---------------------------------------------------------------------------
// Shared GEMM inner loop: acc[n] += Ahi*Bhi + Ahi*Blo + Alo*Bhi
// A-fragment: row = l&15, k = (l>>4)*8 + j ; B-fragment: col = l&15, same k.
// C/D: col = l&15, row = (l>>4)*4 + reg.
// ---------------------------------------------------------------------------
__device__ __forceinline__ void gemm_core(const short8 ah[8], const short8 al[8],
                                          const unsigned short* __restrict__ WThi,
                                          const unsigned short* __restrict__ WTlo,
                                          int l15, int lg, f32x4 acc[16]) {
#pragma unroll
    for (int ks = 0; ks < 8; ++ks) {
#pragma unroll
        for (int n = 0; n < 16; ++n) {
            short8 bh = ld8(&WThi[(n * 16 + l15) * 256 + ks * 32 + lg * 8]);
            short8 bl = ld8(&WTlo[(n * 16 + l15) * 256 + ks * 32 + lg * 8]);
            acc[n] = MFMA16(ah[ks], bh, acc[n]);
            acc[n] = MFMA16(ah[ks], bl, acc[n]);
            acc[n] = MFMA16(al[ks], bh, acc[n]);
        }
    }
}

// ---------------------------------------------------------------------------
// 2. Projections: blockIdx.y selects job (0:Q, 1:K, 2:V).  M=8192 rows,
//    BM=64 (4 waves x 16 rows), N=K=256 full.  Splits fp32 X on the fly.
// ---------------------------------------------------------------------------
__global__ __launch_bounds__(256, 2) void proj3_kernel(
    const float* __restrict__ query, const float* __restrict__ kv,
    const float* __restrict__ rel,
    const unsigned short* __restrict__ WThi, const unsigned short* __restrict__ WTlo,
    const float* __restrict__ bq, const float* __restrict__ bk, const float* __restrict__ bv,
    unsigned short* __restrict__ Qhi, unsigned short* __restrict__ Qlo,
    unsigned short* __restrict__ Khi, unsigned short* __restrict__ Klo,
    unsigned short* __restrict__ Vtmp) {
    const int job = blockIdx.y;
    const float* X = (job == 0) ? query : kv;
    const unsigned short* wh = WThi + job * 65536;
    const unsigned short* wl = WTlo + job * 65536;
    const float* bias = (job == 0) ? bq : (job == 1) ? bk : bv;
    const float* rs = (job == 0) ? nullptr : rel;
    unsigned short* ohi = (job == 0) ? Qhi : (job == 1) ? Khi : Vtmp;
    unsigned short* olo = (job == 0) ? Qlo : (job == 1) ? Klo : nullptr;

    const int w = threadIdx.x >> 6, l = threadIdx.x & 63;
    const int l15 = l & 15, lg = l >> 4;
    const int arow = blockIdx.x * 64 + w * 16 + l15;

    short8 ah[8], al[8];
#pragma unroll
    for (int ks = 0; ks < 8; ++ks) {
        const float* p = &X[arow * 256 + ks * 32 + lg * 8];
        float4 f0 = *reinterpret_cast<const float4*>(p);
        float4 f1 = *reinterpret_cast<const float4*>(p + 4);
        float vv[8] = {f0.x, f0.y, f0.z, f0.w, f1.x, f1.y, f1.z, f1.w};
#pragma unroll
        for (int j = 0; j < 8; ++j) {
            unsigned short h = f2bf(vv[j]);
            ah[ks][j] = (short)h;
            al[ks][j] = (short)f2bf(vv[j] - bf2f(h));
        }
    }
    f32x4 acc[16];
#pragma unroll
    for (int n = 0; n < 16; ++n) acc[n] = (f32x4){0.f, 0.f, 0.f, 0.f};
    gemm_core(ah, al, wh, wl, l15, lg, acc);

    const int orow0 = blockIdx.x * 64 + w * 16 + lg * 4;
    float rsv[4];
#pragma unroll
    for (int r = 0; r < 4; ++r) rsv[r] = rs ? rs[orow0 + r] : 1.0f;
#pragma unroll
    for (int n = 0; n < 16; ++n) {
        const int col = n * 16 + l15;
        const float bn = bias[col];
#pragma unroll
        for (int r = 0; r < 4; ++r) {
            float c = (acc[n][r] + bn) * rsv[r];
            unsigned short h = f2bf(c);
            ohi[(orow0 + r) * 256 + col] = h;
            if (olo) olo[(orow0 + r) * 256 + col] = f2bf(c - bf2f(h));
        }
    }
}

// ---------------------------------------------------------------------------
// 3. Transpose V: [b][k][256] -> Vt [b][256][2048]  (bf16)
// ---------------------------------------------------------------------------
__global__ void transpose_v_kernel(const unsigned short* __restrict__ Vtmp,
                                   unsigned short* __restrict__ Vt) {
    __shared__ unsigned short tile[32][36];
    const int b = blockIdx.z;
    const int k0 = blockIdx.x * 32, d0 = blockIdx.y * 32;
    const int t = threadIdx.x;
    {
        int kr = t >> 3, dc4 = (t & 7) * 4;
        ushort4 v = *reinterpret_cast<const ushort4*>(&Vtmp[(b * 2048 + k0 + kr) * 256 + d0 + dc4]);
        tile[kr][dc4 + 0] = v.x; tile[kr][dc4 + 1] = v.y;
        tile[kr][dc4 + 2] = v.z; tile[kr][dc4 + 3] = v.w;
    }
    __syncthreads();
    {
        int dr = t >> 3, kc4 = (t & 7) * 4;
        ushort4 o;
        o.x = tile[kc4 + 0][dr]; o.y = tile[kc4 + 1][dr];
        o.z = tile[kc4 + 2][dr]; o.w = tile[kc4 + 3][dr];
        *reinterpret_cast<ushort4*>(&Vt[(b * 256 + d0 + dr) * 2048 + k0 + kc4]) = o;
    }
}

// ---------------------------------------------------------------------------
// 4. Attention.  Block: 512 thr = 8 waves = (qh in 0..1) x (kh in 0..3).
//    Each wave: 16 q-rows, all 4 heads, k-tiles kt = kh, kh+4, ...
//    Pass 1: s[h][q] = sum_k exp(S*0.125)*r     (no max needed: |logit|<~10)
//    Pass 2: p = exp(S*0.125)*r/s ; attn_mean += p/4 ; PV via LDS-staged P.
// ---------------------------------------------------------------------------
__global__ __launch_bounds__(512, 2) void attn_kernel(
    const unsigned short* __restrict__ Qhi, const unsigned short* __restrict__ Qlo,
    const unsigned short* __restrict__ Khi, const unsigned short* __restrict__ Klo,
    const unsigned short* __restrict__ Vt, const float* __restrict__ rel,
    float* __restrict__ attn_mean,
    unsigned short* __restrict__ AOhi, unsigned short* __restrict__ AOlo) {
    const int b = blockIdx.y;
    const int q0 = blockIdx.x * 32;
    const int tid = threadIdx.x;
    const int w = tid >> 6;
    const int qh = w >> 2, kh = w & 3;
    const int l = tid & 63, l15 = l & 15, lg = l >> 4;
    const float C = 0.125f;

    __shared__ float ssum_lds[4][4][32];
    __shared__ float sinv_lds[4][32];
    __shared__ __align__(16) unsigned short pstage[8][4][16][40]; // [wave][head][row][k]
    __shared__ float obuf[32][256];

    // Q fragments (A-frag: row = l15)
    short8 qfh[4][2], qfl[4][2];
    {
        const int qrow = b * 2048 + q0 + qh * 16 + l15;
#pragma unroll
        for (int h = 0; h < 4; ++h)
#pragma unroll
            for (int kd = 0; kd < 2; ++kd) {
                int off = qrow * 256 + h * 64 + kd * 32 + lg * 8;
                qfh[h][kd] = ld8(&Qhi[off]);
                qfl[h][kd] = ld8(&Qlo[off]);
            }
    }

    // ---------------- pass 1: row sums ----------------
    float ssum[4][4];
#pragma unroll
    for (int h = 0; h < 4; ++h)
#pragma unroll
        for (int r = 0; r < 4; ++r) ssum[h][r] = 0.f;

    for (int kt = kh; kt < 64; kt += 4) {
#pragma unroll
        for (int kc = 0; kc < 2; ++kc) {
            const int krow = b * 2048 + kt * 32 + kc * 16 + l15;
            const float rc = fmaxf(rel[krow], 1e-6f);
#pragma unroll
            for (int h = 0; h < 4; ++h) {
                f32x4 acc = (f32x4){0.f, 0.f, 0.f, 0.f};
#pragma unroll
                for (int kd = 0; kd < 2; ++kd) {
                    int off = krow * 256 + h * 64 + kd * 32 + lg * 8;
                    short8 bhf = ld8(&Khi[off]);
                    short8 blf = ld8(&Klo[off]);
                    acc = MFMA16(qfh[h][kd], bhf, acc);
                    acc = MFMA16(qfh[h][kd], blf, acc);
                    acc = MFMA16(qfl[h][kd], bhf, acc);
                }
#pragma unroll
                for (int r = 0; r < 4; ++r)
                    ssum[h][r] += __expf(acc[r] * C) * rc;
            }
        }
    }
    // reduce across the 16 column-lanes
#pragma unroll
    for (int h = 0; h < 4; ++h)
#pragma unroll
        for (int r = 0; r < 4; ++r) {
            float v = ssum[h][r];
            v += __shfl_xor(v, 1); v += __shfl_xor(v, 2);
            v += __shfl_xor(v, 4); v += __shfl_xor(v, 8);
            ssum[h][r] = v;
        }
    if (l15 == 0) {
#pragma unroll
        for (int h = 0; h < 4; ++h)
#pragma unroll
            for (int r = 0; r < 4; ++r)
                ssum_lds[kh][h][qh * 16 + lg * 4 + r] = ssum[h][r];
    }
    __syncthreads();
    if (tid < 128) {
        int h = tid >> 5, q = tid & 31;
        float s = ssum_lds[0][h][q] + ssum_lds[1][h][q] + ssum_lds[2][h][q] + ssum_lds[3][h][q];
        sinv_lds[h][q] = 1.0f / s;
    }
    __syncthreads();

    float si[4][4];
#pragma unroll
    for (int h = 0; h < 4; ++h)
#pragma unroll
        for (int r = 0; r < 4; ++r) si[h][r] = sinv_lds[h][qh * 16 + lg * 4 + r];

    // ---------------- pass 2: probabilities + PV ----------------
    f32x4 oacc[4][4];
#pragma unroll
    for (int h = 0; h < 4; ++h)
#pragma unroll
        for (int dc = 0; dc < 4; ++dc) oacc[h][dc] = (f32x4){0.f, 0.f, 0.f, 0.f};

    for (int kt = kh; kt < 64; kt += 4) {
        float pm[2][4] = {{0.f, 0.f, 0.f, 0.f}, {0.f, 0.f, 0.f, 0.f}};
#pragma unroll
        for (int h = 0; h < 4; ++h) {
#pragma unroll
            for (int kc = 0; kc < 2; ++kc) {
                const int krow = b * 2048 + kt * 32 + kc * 16 + l15;
                const float rc = fmaxf(rel[krow], 1e-6f);
                f32x4 acc = (f32x4){0.f, 0.f, 0.f, 0.f};
#pragma unroll
                for (int kd = 0; kd < 2; ++kd) {
                    int off = krow * 256 + h * 64 + kd * 32 + lg * 8;
                    short8 bhf = ld8(&Khi[off]);
                    short8 blf = ld8(&Klo[off]);
                    acc = MFMA16(qfh[h][kd], bhf, acc);
                    acc = MFMA16(qfh[h][kd], blf, acc);
                    acc = MFMA16(qfl[h][kd], bhf, acc);
                }
#pragma unroll
                for (int r = 0; r < 4; ++r) {
                    float p = __expf(acc[r] * C) * rc * si[h][r];
                    pm[kc][r] += p;
                    pstage[w][h][lg * 4 + r][kc * 16 + l15] = f2bf(p);
                }
            }
            // PV: A-frag of P from LDS (same-wave RAW, in-order DS)
            short8 pa = ld8(&pstage[w][h][l15][lg * 8]);
#pragma unroll
            for (int dc = 0; dc < 4; ++dc) {
                short8 vb = ld8(&Vt[(b * 256 + h * 64 + dc * 16 + l15) * 2048 + kt * 32 + lg * 8]);
                oacc[h][dc] = MFMA16(pa, vb, oacc[h][dc]);
            }
        }
        // write head-mean probabilities
#pragma unroll
        for (int kc = 0; kc < 2; ++kc)
#pragma unroll
            for (int r = 0; r < 4; ++r)
                attn_mean[(size_t)(b * 2048 + q0 + qh * 16 + lg * 4 + r) * 2048 +
                          kt * 32 + kc * 16 + l15] = pm[kc][r] * 0.25f;
    }

    // ---------------- combine PV partials across the 4 k-split waves --------
    for (int wi = 0; wi < 4; ++wi) {
        __syncthreads();
        if (kh == wi) {
#pragma unroll
            for (int h = 0; h < 4; ++h)
#pragma unroll
                for (int dc = 0; dc < 4; ++dc)
#pragma unroll
                    for (int r = 0; r < 4; ++r) {
                        int rr = qh * 16 + lg * 4 + r;
                        int cc = h * 64 + dc * 16 + l15;
                        if (wi == 0) obuf[rr][cc] = oacc[h][dc][r];
                        else obuf[rr][cc] += oacc[h][dc][r];
                    }
        }
    }
    __syncthreads();
    {
        const int row = tid >> 4;            // 0..31
        const int col0 = (tid & 15) * 16;
        const int orow = b * 2048 + q0 + row;
#pragma unroll
        for (int j = 0; j < 16; ++j) {
            float v = obuf[row][col0 + j];
            unsigned short h = f2bf(v);
            AOhi[orow * 256 + col0 + j] = h;
            AOlo[orow * 256 + col0 + j] = f2bf(v - bf2f(h));
        }
    }
}

// ---------------------------------------------------------------------------
// 5. out = AO @ Wo + bo   (AO pre-split, fp32 output)
// ---------------------------------------------------------------------------
__global__ __launch_bounds__(256, 2) void final_kernel(
    const unsigned short* __restrict__ AOhi, const unsigned short* __restrict__ AOlo,
    const unsigned short* __restrict__ WThi, const unsigned short* __restrict__ WTlo,
    const float* __restrict__ bo, float* __restrict__ out) {
    const int w = threadIdx.x >> 6, l = threadIdx.x & 63;
    const int l15 = l & 15, lg = l >> 4;
    const int arow = blockIdx.x * 64 + w * 16 + l15;
    short8 ah[8], al[8];
#pragma unroll
    for (int ks = 0; ks < 8; ++ks) {
        ah[ks] = ld8(&AOhi[arow * 256 + ks * 32 + lg * 8]);
        al[ks] = ld8(&AOlo[arow * 256 + ks * 32 + lg * 8]);
    }
    f32x4 acc[16];
#pragma unroll
    for (int n = 0; n < 16; ++n) acc[n] = (f32x4){0.f, 0.f, 0.f, 0.f};
    gemm_core(ah, al, WThi, WTlo, l15, lg, acc);

    const int orow0 = blockIdx.x * 64 + w * 16 + lg * 4;
#pragma unroll
    for (int n = 0; n < 16; ++n) {
        const int col = n * 16 + l15;
        const float bn = bo[col];
#pragma unroll
        for (int r = 0; r < 4; ++r)
            out[(orow0 + r) * 256 + col] = acc[n][r] + bn;
    }
}

// ---------------------------------------------------------------------------
extern "C" void kernel_launch(void* const* d_in, const int* in_sizes, int n_in,
                              void* d_out, int out_size, void* d_ws, size_t ws_size,
                              hipStream_t stream) {
    const float* query = (const float*)d_in[0];
    const float* kv    = (const float*)d_in[1];
    const float* rel   = (const float*)d_in[2];
    const float* Wq    = (const float*)d_in[3];
    const float* bq    = (const float*)d_in[4];
    const float* Wk    = (const float*)d_in[5];
    const float* bk    = (const float*)d_in[6];
    const float* Wv    = (const float*)d_in[7];
    const float* bv    = (const float*)d_in[8];
    const float* Wo    = (const float*)d_in[9];
    const float* bo    = (const float*)d_in[10];

    char* ws = (char*)d_ws;
    unsigned short* WThi = (unsigned short*)(ws + 0);          // 4*64K*2B = 512KB
    unsigned short* WTlo = (unsigned short*)(ws + 524288);     // 512KB
    unsigned short* Qhi  = (unsigned short*)(ws + 1048576);    // 4MB each below
    unsigned short* Qlo  = (unsigned short*)(ws + 5242880);
    unsigned short* Khi  = (unsigned short*)(ws + 9437184);
    unsigned short* Klo  = (unsigned short*)(ws + 13631488);
    unsigned short* Vtmp = (unsigned short*)(ws + 17825792);
    unsigned short* Vt   = (unsigned short*)(ws + 22020096);
    unsigned short* AOhi = (unsigned short*)(ws + 26214400);
    unsigned short* AOlo = (unsigned short*)(ws + 30408704);   // end = 34603008

    float* out = (float*)d_out;
    float* attn_mean = (float*)d_out + 2097152;

    wsplit_kernel<<<1024, 256, 0, stream>>>(Wq, Wk, Wv, Wo, WThi, WTlo);
    proj3_kernel<<<dim3(128, 3), 256, 0, stream>>>(query, kv, rel, WThi, WTlo,
                                                   bq, bk, bv, Qhi, Qlo, Khi, Klo, Vtmp);
    transpose_v_kernel<<<dim3(64, 8, 4), 256, 0, stream>>>(Vtmp, Vt);
    attn_kernel<<<dim3(64, 4), 512, 0, stream>>>(Qhi, Qlo, Khi, Klo, Vt, rel,
                                                 attn_mean, AOhi, AOlo);
    final_kernel<<<128, 256, 0, stream>>>(AOhi, AOlo, WThi + 3 * 65536, WTlo + 3 * 65536,
                                          bo, out);
}